// Round 1
// baseline (136.178 us; speedup 1.0000x reference)
//
#include <hip/hip_runtime.h>

// Problem dims (hard-coded in reference)
#define DD   768
#define NN   512
#define MM   512

#define PRE_K 2.88539008177792681472f   // 2*log2(e)

typedef _Float16 h8 __attribute__((ext_vector_type(8)));  // 8 f16 (4 VGPRs)
typedef __attribute__((ext_vector_type(4))) float f32x4;  // MFMA C/D

__device__ __forceinline__ float fexp(float x) { return __builtin_amdgcn_exp2f(x); }
__device__ __forceinline__ float frcp(float x) { return __builtin_amdgcn_rcpf(x); }
// tanh(x) = 1 - 2/(1 + e^{2x}); saturates correctly via exp2->inf/0 + rcp.
__device__ __forceinline__ float fast_tanh(float x) {
  return 1.0f - 2.0f * frcp(fexp(PRE_K * x) + 1.0f);
}
// R13 lesson: Schraudolph fast-exp2 REGRESSED (45.0 -> 47.4, VALUBusy 69->79%):
// the ALU replacement issues MORE full-rate slots than one quarter-rate v_exp.
// Keep the hardware transcendental.

// fp32 -> f16 hi/lo split (pair covers ~21 mantissa bits)
__device__ __forceinline__ void splitf(float x, ushort& h, ushort& l) {
  const _Float16 hh = (_Float16)x;
  const _Float16 ll = (_Float16)(x - (float)hh);
  h = __builtin_bit_cast(unsigned short, hh);
  l = __builtin_bit_cast(unsigned short, ll);
}

// ---- fused prep ------------------------------------------------------------
// blocks [0,1344): elementwise f16 hi/lo split of text/visual/W3
// blocks [1344,2496): transpose+split W1/W2 -> [j][k]
// (T-init branch removed: main now computes tsum in-register and stores out
//  directly — no atomics, no out pre-init.)
__global__ __launch_bounds__(256) void prep_kernel(
    const float* __restrict__ text, const float* __restrict__ visual,
    const float* __restrict__ W1, const float* __restrict__ W2,
    const float* __restrict__ W3,
    ushort* __restrict__ th, ushort* __restrict__ tl,
    ushort* __restrict__ vh, ushort* __restrict__ vl,
    ushort* __restrict__ w3h, ushort* __restrict__ w3l,
    ushort* __restrict__ w1th, ushort* __restrict__ w1tl,
    ushort* __restrict__ w2th, ushort* __restrict__ w2tl)
{
  __shared__ float Lt[32][33];
  const int b = blockIdx.x;
  const int t = threadIdx.x;

  if (b < 1344) {
    const float* src; ushort *dh, *dl; size_t off;
    if (b < 384)      { src = text;   dh = th;  dl = tl;  off = (size_t)b * 1024; }
    else if (b < 768) { src = visual; dh = vh;  dl = vl;  off = (size_t)(b - 384) * 1024; }
    else              { src = W3;     dh = w3h; dl = w3l; off = (size_t)(b - 768) * 1024; }
    const size_t i = off + (size_t)t * 4;
    const float4 v = *(const float4*)&src[i];
    ushort4 h, l;
    splitf(v.x, h.x, l.x); splitf(v.y, h.y, l.y);
    splitf(v.z, h.z, l.z); splitf(v.w, h.w, l.w);
    *(ushort4*)&dh[i] = h;
    *(ushort4*)&dl[i] = l;
  } else {
    const int tt = b - 1344;
    const bool second = tt >= 576;
    const int tile = second ? tt - 576 : tt;
    const float* W = second ? W2 : W1;
    ushort* oh = second ? w2th : w1th;
    ushort* ol = second ? w2tl : w1tl;
    const int k0 = (tile / 24) * 32, j0 = (tile % 24) * 32;
    {
      const int k = t >> 3, j4 = (t & 7) * 4;
      const float4 v = *(const float4*)&W[(size_t)(k0 + k) * DD + j0 + j4];
      Lt[j4 + 0][k] = v.x; Lt[j4 + 1][k] = v.y;
      Lt[j4 + 2][k] = v.z; Lt[j4 + 3][k] = v.w;
    }
    __syncthreads();
    {
      const int j = t >> 3, k4 = (t & 7) * 4;
      ushort4 h, l;
      splitf(Lt[j][k4 + 0], h.x, l.x); splitf(Lt[j][k4 + 1], h.y, l.y);
      splitf(Lt[j][k4 + 2], h.z, l.z); splitf(Lt[j][k4 + 3], h.w, l.w);
      *(ushort4*)&oh[(size_t)(j0 + j) * DD + k0 + k4] = h;
      *(ushort4*)&ol[(size_t)(j0 + j) * DD + k0 + k4] = l;
    }
  }
}

// ---- staged-LDS MFMA GEMM core, 32x64 tile (R14: occupancy re-tile) --------
// Old 64x64 tiling gave only 288/256-block grids = 1 wave/SIMD: every K-step
// exposed full memory latency. 32x64 doubles the grid (576 blocks, 2.25/CU
// co-resident, LDS 30KB) so a second block's waves cover the staging stalls.
// ALO=false drops the a_lo*b_hi term (and a_lo staging): used for kw2t/kw3v.
#define BK   32
#define LROW 40            // padded LDS row stride (f16): 2-way banks, 16B-aligned
#define APL  (32 * LROW)   // one A plane (rows x LROW)
#define BPL  (64 * LROW)   // one B plane

template <bool ALO>
__device__ __forceinline__ void gemm_core32(
    ushort* __restrict__ As, ushort* __restrict__ Bs,   // [2 buf][2 hi/lo][plane]
    const ushort* __restrict__ Ahg, const ushort* __restrict__ Alg,
    const ushort* __restrict__ Bhg, const ushort* __restrict__ Blg,
    int i0, int j0, int nsteps, f32x4* acc)
{
  const int tid = threadIdx.x;
  const int row = tid >> 2;             // 0..63 staging row (B); 0..31 for A
  const int ks8 = (tid & 3) * 8;        // 0,8,16,24 (f16)
  const bool doA = (row < 32);          // waves 0,1 stage A too (wave-uniform)
  const size_t ga = (size_t)(i0 + row) * DD + ks8;
  const size_t gb = (size_t)(j0 + row) * DD + ks8;
  const int lw = row * LROW + ks8;

  const int lane = tid & 63, wave = tid >> 6;
  const int r15 = lane & 15, quad = lane >> 4;
  const int wr = wave >> 1, wc = wave & 1;              // 2x2 wave grid
  const int fa = (wr * 16 + r15) * LROW + quad * 8;     // A frag offset
  const int fb = (wc * 32 + r15) * LROW + quad * 8;     // B frag base

  h8 pah, pal, pbh, pbl;
  if (doA) {
    pah = *(const h8*)(Ahg + ga);
    if (ALO) pal = *(const h8*)(Alg + ga);
  }
  pbh = *(const h8*)(Bhg + gb);
  pbl = *(const h8*)(Blg + gb);

  int p = 0;
  if (doA) {
    *(h8*)&As[lw] = pah;
    if (ALO) *(h8*)&As[APL + lw] = pal;
  }
  *(h8*)&Bs[lw] = pbh;
  *(h8*)&Bs[BPL + lw] = pbl;
  __syncthreads();

  for (int s = 0; s < nsteps; ++s) {
    const bool more = (s + 1 < nsteps);
    if (more) {  // issue next chunk's globals; MFMA below hides latency
      if (doA) {
        pah = *(const h8*)(Ahg + ga + (s + 1) * BK);
        if (ALO) pal = *(const h8*)(Alg + ga + (s + 1) * BK);
      }
      pbh = *(const h8*)(Bhg + gb + (s + 1) * BK);
      pbl = *(const h8*)(Blg + gb + (s + 1) * BK);
    }
    ushort* Ac = As + p * 2 * APL;
    ushort* Bc = Bs + p * 2 * BPL;
    const h8 a_h = *(const h8*)&Ac[fa];
    h8 a_l; if (ALO) a_l = *(const h8*)&Ac[APL + fa];
    h8 b_h[2], b_l[2];
    #pragma unroll
    for (int c = 0; c < 2; ++c) {
      b_h[c] = *(const h8*)&Bc[fb + c * 16 * LROW];
      b_l[c] = *(const h8*)&Bc[BPL + fb + c * 16 * LROW];
    }
    #pragma unroll
    for (int c = 0; c < 2; ++c)
      acc[c] = __builtin_amdgcn_mfma_f32_16x16x32_f16(a_h, b_h[c], acc[c], 0, 0, 0);
    #pragma unroll
    for (int c = 0; c < 2; ++c)
      acc[c] = __builtin_amdgcn_mfma_f32_16x16x32_f16(a_h, b_l[c], acc[c], 0, 0, 0);
    if (ALO) {
      #pragma unroll
      for (int c = 0; c < 2; ++c)
        acc[c] = __builtin_amdgcn_mfma_f32_16x16x32_f16(a_l, b_h[c], acc[c], 0, 0, 0);
    }
    if (more) {
      const int q = p ^ 1;
      ushort* An = As + q * 2 * APL;
      ushort* Bn = Bs + q * 2 * BPL;
      if (doA) {
        *(h8*)&An[lw] = pah;
        if (ALO) *(h8*)&An[APL + lw] = pal;
      }
      *(h8*)&Bn[lw] = pbh;
      *(h8*)&Bn[BPL + lw] = pbl;
    }
    __syncthreads();
    p ^= 1;
  }
}

// z=0: A=text@W1 -> Ah/Al(f16)  z=1: kw2t=PRE_K*text@W2  z=2: kw3v=PRE_K*visual@W3^T
// grid (DD/64, NN/32, 3) = (12, 16, 3) = 576 blocks.
__global__ __launch_bounds__(256) void mfma1_kernel(
    const ushort* __restrict__ th, const ushort* __restrict__ tl,
    const ushort* __restrict__ vh, const ushort* __restrict__ vl,
    const ushort* __restrict__ w1th, const ushort* __restrict__ w1tl,
    const ushort* __restrict__ w2th, const ushort* __restrict__ w2tl,
    const ushort* __restrict__ w3h, const ushort* __restrict__ w3l,
    ushort* __restrict__ Ah, ushort* __restrict__ Al,
    float* __restrict__ kw2t, float* __restrict__ kw3v)
{
  __shared__ ushort As[2 * 2 * APL];   // 10240 B
  __shared__ ushort Bs[2 * 2 * BPL];   // 20480 B

  const int z  = blockIdx.z;
  const int j0 = blockIdx.x * 64;
  const int i0 = blockIdx.y * 32;

  f32x4 acc[2];
  acc[0] = (f32x4){0.f, 0.f, 0.f, 0.f};
  acc[1] = (f32x4){0.f, 0.f, 0.f, 0.f};

  if (z == 0)
    gemm_core32<true >(As, Bs, th, tl, w1th, w1tl, i0, j0, DD / BK, acc);
  else if (z == 1)
    gemm_core32<false>(As, Bs, th, tl, w2th, w2tl, i0, j0, DD / BK, acc);
  else
    gemm_core32<false>(As, Bs, vh, vl, w3h,  w3l,  i0, j0, DD / BK, acc);

  const int lane = threadIdx.x & 63, wave = threadIdx.x >> 6;
  const int r15 = lane & 15, quad = lane >> 4;
  const int wr = wave >> 1, wc = wave & 1;
  // C/D layout: col=lane&15 (B row j), row=quad*4+reg (A row i)
  if (z == 0) {
    #pragma unroll
    for (int c = 0; c < 2; ++c)
      #pragma unroll
      for (int r = 0; r < 4; ++r) {
        const size_t o = (size_t)(i0 + wr * 16 + quad * 4 + r) * DD
                       + j0 + wc * 32 + c * 16 + r15;
        splitf(acc[c][r], Ah[o], Al[o]);
      }
  } else {
    float* Out = (z == 1) ? kw2t : kw3v;
    #pragma unroll
    for (int c = 0; c < 2; ++c)
      #pragma unroll
      for (int r = 0; r < 4; ++r)
        Out[(size_t)(i0 + wr * 16 + quad * 4 + r) * DD + j0 + wc * 32 + c * 16 + r15] =
            acc[c][r] * PRE_K;
  }
}

// ---- main fused kernel (R14: mfma2 fused in as phase 1) --------------------
// Phase 1 (idle-MFMA-pipe): per block, Qtile[16][32] = (A @ visual^T) with the
// f16 hi/lo 3-product scheme, K split across the 4 waves (wave w = K-quarter w,
// mirroring the old mfma2 z-split summation order exactly). Register-direct
// fragments, no LDS staging. Then cval = tanh(sum of 4 partials).
// Phase 2: out[n,m] = tsum[n] - 2 * sum_d text[n,d]*rcp(1+exp2(kw2t+kw3v*cval))
// Full D per block -> each out element written once: direct store, no atomics.
#define DCH  64
#define MLDW 68
#define NCH  (DD / DCH)   // 12

__global__ __launch_bounds__(256) void main_kernel(
    const float* __restrict__ text, const float* __restrict__ kw2t,
    const float* __restrict__ kw3v,
    const ushort* __restrict__ Ah, const ushort* __restrict__ Al,
    const ushort* __restrict__ vh, const ushort* __restrict__ vl,
    float* __restrict__ out)
{
  __shared__ float sbuf[2][64 * MLDW];   // 34816 B; phase-1 Qs aliases front 8KB

  const int tid = threadIdx.x;
  const int nl = tid >> 4;
  const int ml = tid & 15;
  const int n0 = blockIdx.y * 16;
  const int m0 = blockIdx.x * 32;
  const int lane = tid & 63, wave = tid >> 6;
  const int r15 = lane & 15, quad = lane >> 4;

  // ---- phase 1: Q tile via MFMA, K-quarter per wave
  const size_t aoff  = (size_t)(n0 + r15) * DD + wave * (DD / 4) + quad * 8;
  const size_t b0off = (size_t)(m0 + r15) * DD + wave * (DD / 4) + quad * 8;
  const size_t b1off = (size_t)(m0 + 16 + r15) * DD + wave * (DD / 4) + quad * 8;
  const ushort* Ap  = Ah + aoff;
  const ushort* Alp = Al + aoff;
  const ushort* B0h = vh + b0off;
  const ushort* B0l = vl + b0off;
  const ushort* B1h = vh + b1off;
  const ushort* B1l = vl + b1off;

  f32x4 q0 = {0.f, 0.f, 0.f, 0.f}, q1 = {0.f, 0.f, 0.f, 0.f};
  h8 cah  = *(const h8*)Ap;
  h8 cal  = *(const h8*)Alp;
  h8 cb0h = *(const h8*)B0h;
  h8 cb0l = *(const h8*)B0l;
  h8 cb1h = *(const h8*)B1h;
  h8 cb1l = *(const h8*)B1l;
  #pragma unroll
  for (int s = 0; s < (DD / 4) / BK; ++s) {   // 6 steps
    h8 nah, nal, nb0h, nb0l, nb1h, nb1l;
    const bool more = (s + 1 < (DD / 4) / BK);
    if (more) {
      nah  = *(const h8*)(Ap  + (s + 1) * BK);
      nal  = *(const h8*)(Alp + (s + 1) * BK);
      nb0h = *(const h8*)(B0h + (s + 1) * BK);
      nb0l = *(const h8*)(B0l + (s + 1) * BK);
      nb1h = *(const h8*)(B1h + (s + 1) * BK);
      nb1l = *(const h8*)(B1l + (s + 1) * BK);
    }
    // per-acc product order hh, hl, lh matches old mfma2/gemm_core exactly
    q0 = __builtin_amdgcn_mfma_f32_16x16x32_f16(cah, cb0h, q0, 0, 0, 0);
    q1 = __builtin_amdgcn_mfma_f32_16x16x32_f16(cah, cb1h, q1, 0, 0, 0);
    q0 = __builtin_amdgcn_mfma_f32_16x16x32_f16(cah, cb0l, q0, 0, 0, 0);
    q1 = __builtin_amdgcn_mfma_f32_16x16x32_f16(cah, cb1l, q1, 0, 0, 0);
    q0 = __builtin_amdgcn_mfma_f32_16x16x32_f16(cal, cb0h, q0, 0, 0, 0);
    q1 = __builtin_amdgcn_mfma_f32_16x16x32_f16(cal, cb1h, q1, 0, 0, 0);
    if (more) { cah = nah; cal = nal; cb0h = nb0h; cb0l = nb0l; cb1h = nb1h; cb1l = nb1l; }
  }

  float (*Qs)[16][32] = (float (*)[16][32])(&sbuf[0][0]);   // 8 KB alias
  #pragma unroll
  for (int r = 0; r < 4; ++r) {
    Qs[wave][quad * 4 + r][r15]      = q0[r];
    Qs[wave][quad * 4 + r][16 + r15] = q1[r];
  }
  __syncthreads();
  float sA = Qs[0][nl][ml];
  sA += Qs[1][nl][ml]; sA += Qs[2][nl][ml]; sA += Qs[3][nl][ml];
  float sB = Qs[0][nl][ml + 16];
  sB += Qs[1][nl][ml + 16]; sB += Qs[2][nl][ml + 16]; sB += Qs[3][nl][ml + 16];
  const float cA = fast_tanh(sA);
  const float cB = fast_tanh(sB);
  __syncthreads();   // Qs dead; sbuf reused by phase 2

  // ---- phase 2: transcendental loop (R11-proven structure, full D)
  const int n  = n0 + nl;
  const int mA = m0 + ml, mB = mA + 16;

  float4 aA = {0.f, 0.f, 0.f, 0.f};
  float4 aB = {0.f, 0.f, 0.f, 0.f};
  float4 ts = {0.f, 0.f, 0.f, 0.f};   // tsum: replaces prep's T-init + atomics

  const int srow = tid >> 4;              // staging row 0..15
  const int sc4  = (tid & 15) << 2;       // staging col 0..60
  const float* gt  = &text[(size_t)(n0 + srow) * DD + sc4];
  const float* g2  = &kw2t[(size_t)(n0 + srow) * DD + sc4];
  const float* g3a = &kw3v[(size_t)(m0 + srow) * DD + sc4];
  const float* g3b = &kw3v[(size_t)(m0 + 16 + srow) * DD + sc4];
  const int wt  = srow * MLDW + sc4;          // text rows
  const int w2  = (16 + srow) * MLDW + sc4;   // kw2t rows
  const int w3a = (32 + srow) * MLDW + sc4;   // kw3v rows (first 16)
  const int w3b = (48 + srow) * MLDW + sc4;   // kw3v rows (second 16)

  // prologue: stage chunk 0 into buffer 0
  float4 rt  = *(const float4*)gt;
  float4 r2  = *(const float4*)g2;
  float4 r3a = *(const float4*)g3a;
  float4 r3b = *(const float4*)g3b;
  int p = 0;
  *(float4*)&sbuf[0][wt]  = rt;
  *(float4*)&sbuf[0][w2]  = r2;
  *(float4*)&sbuf[0][w3a] = r3a;
  *(float4*)&sbuf[0][w3b] = r3b;
  __syncthreads();

  #pragma unroll 4
  for (int c = 0; c < NCH; ++c) {
    const bool more = (c + 1 < NCH);
    if (more) {  // prefetch next chunk; compute below hides latency
      rt  = *(const float4*)(gt  + (c + 1) * DCH);
      r2  = *(const float4*)(g2  + (c + 1) * DCH);
      r3a = *(const float4*)(g3a + (c + 1) * DCH);
      r3b = *(const float4*)(g3b + (c + 1) * DCH);
    }
    const float* bp = sbuf[p];
    #pragma unroll 4
    for (int j = 0; j < DCH; j += 4) {
      const float4 tv  = *(const float4*)&bp[nl * MLDW + j];
      const float4 w2v = *(const float4*)&bp[(16 + nl) * MLDW + j];
      const float4 w3A = *(const float4*)&bp[(32 + ml) * MLDW + j];
      const float4 w3B = *(const float4*)&bp[(48 + ml) * MLDW + j];
      ts.x += tv.x; ts.y += tv.y; ts.z += tv.z; ts.w += tv.w;
      aA.x = fmaf(tv.x, frcp(fexp(fmaf(w3A.x, cA, w2v.x)) + 1.0f), aA.x);
      aA.y = fmaf(tv.y, frcp(fexp(fmaf(w3A.y, cA, w2v.y)) + 1.0f), aA.y);
      aA.z = fmaf(tv.z, frcp(fexp(fmaf(w3A.z, cA, w2v.z)) + 1.0f), aA.z);
      aA.w = fmaf(tv.w, frcp(fexp(fmaf(w3A.w, cA, w2v.w)) + 1.0f), aA.w);
      aB.x = fmaf(tv.x, frcp(fexp(fmaf(w3B.x, cB, w2v.x)) + 1.0f), aB.x);
      aB.y = fmaf(tv.y, frcp(fexp(fmaf(w3B.y, cB, w2v.y)) + 1.0f), aB.y);
      aB.z = fmaf(tv.z, frcp(fexp(fmaf(w3B.z, cB, w2v.z)) + 1.0f), aB.z);
      aB.w = fmaf(tv.w, frcp(fexp(fmaf(w3B.w, cB, w2v.w)) + 1.0f), aB.w);
    }
    if (more) {
      const int q = p ^ 1;
      *(float4*)&sbuf[q][wt]  = rt;
      *(float4*)&sbuf[q][w2]  = r2;
      *(float4*)&sbuf[q][w3a] = r3a;
      *(float4*)&sbuf[q][w3b] = r3b;
    }
    __syncthreads();   // single barrier per chunk
    p ^= 1;
  }

  const float tsum = (ts.x + ts.y) + (ts.z + ts.w);
  float* op = out + (size_t)n * MM;
  op[mA] = fmaf(-2.0f, (aA.x + aA.y) + (aA.z + aA.w), tsum);
  op[mB] = fmaf(-2.0f, (aB.x + aB.y) + (aB.z + aB.w), tsum);
}

// ---- launcher --------------------------------------------------------------
extern "C" void kernel_launch(void* const* d_in, const int* in_sizes, int n_in,
                              void* d_out, int out_size, void* d_ws, size_t ws_size,
                              hipStream_t stream) {
  const float* text   = (const float*)d_in[0];
  const float* visual = (const float*)d_in[1];
  const float* W1     = (const float*)d_in[2];
  const float* W2     = (const float*)d_in[3];
  const float* W3     = (const float*)d_in[4];
  float* out = (float*)d_out;

  // Workspace byte layout (peak ~14.9 MB, proven available):
  //   th/tl/vh/vl : f16 hi/lo of text, visual     (4 x 768 KB)
  //   w1t/w2t h,l : f16 hi/lo of W1^T,W2^T [j][k] (4 x 1.125 MB)
  //   w3 h/l      : f16 hi/lo of W3 [j][k]        (2 x 1.125 MB)
  //   Ah/Al       : f16 hi/lo of A                (2 x 768 KB)
  //   kw2t/kw3v   : fp32                          (2 x 1.5 MB)
  // (Q buffer removed: the Q-GEMM is fused into main_kernel phase 1.)
  char* base = (char*)d_ws;
  ushort* th   = (ushort*)(base);
  ushort* tl   = (ushort*)(base + 786432);
  ushort* vh   = (ushort*)(base + 1572864);
  ushort* vl   = (ushort*)(base + 2359296);
  ushort* w1th = (ushort*)(base + 3145728);
  ushort* w1tl = (ushort*)(base + 4325376);
  ushort* w2th = (ushort*)(base + 5505024);
  ushort* w2tl = (ushort*)(base + 6684672);
  ushort* w3h  = (ushort*)(base + 7864320);
  ushort* w3l  = (ushort*)(base + 9043968);
  ushort* Ah   = (ushort*)(base + 10223616);
  ushort* Al   = (ushort*)(base + 11010048);
  float*  kw2t = (float*) (base + 11796480);
  float*  kw3v = (float*) (base + 13369344);

  hipLaunchKernelGGL(prep_kernel, dim3(2496), dim3(256), 0, stream,
                     text, visual, W1, W2, W3,
                     th, tl, vh, vl, w3h, w3l, w1th, w1tl, w2th, w2tl);
  hipLaunchKernelGGL(mfma1_kernel, dim3(DD / 64, NN / 32, 3), dim3(256), 0, stream,
                     th, tl, vh, vl, w1th, w1tl, w2th, w2tl, w3h, w3l,
                     Ah, Al, kw2t, kw3v);
  hipLaunchKernelGGL(main_kernel, dim3(MM / 32, NN / 16), dim3(256), 0, stream,
                     text, kw2t, kw3v, Ah, Al, vh, vl, out);
}